// Round 1
// baseline (553.282 us; speedup 1.0000x reference)
//
#include <hip/hip_runtime.h>

#define RESO 192
#define DATA_DIM 28
#define CHUNKS 7  // DATA_DIM / 4 float4 chunks per point

__device__ __forceinline__ float4 f4_zero() { return make_float4(0.f, 0.f, 0.f, 0.f); }

__device__ __forceinline__ float4 f4_lerp(float4 a, float4 b, float wa, float wb) {
    // a*wa + b*wb, fused
    float4 r;
    r.x = fmaf(a.x, wa, b.x * wb);
    r.y = fmaf(a.y, wa, b.y * wb);
    r.z = fmaf(a.z, wa, b.z * wb);
    r.w = fmaf(a.w, wa, b.w * wb);
    return r;
}

__global__ __launch_bounds__(256) void sparsegrid_sample_kernel(
    const float* __restrict__ points,
    const float* __restrict__ data,
    const int*   __restrict__ links,
    const float* __restrict__ offset,
    const float* __restrict__ scaling,
    float*       __restrict__ out,
    int n_pts)
{
    const int tid = blockIdx.x * blockDim.x + threadIdx.x;
    const int total = n_pts * CHUNKS;
    if (tid >= total) return;

    const int p = tid / CHUNKS;           // point index
    const int c = tid - p * CHUNKS;       // float4 chunk index [0,7)

    // Per-axis coordinate transform (same math as reference, f32 throughout)
    int   l[3];
    float wb[3];
#pragma unroll
    for (int i = 0; i < 3; ++i) {
        const float gsz = (float)RESO;
        float v = fmaf(points[p * 3 + i], scaling[i] * gsz, offset[i] * gsz - 0.5f);
        v = fminf(fmaxf(v, 0.0f), gsz - 1.0f);
        int li = (int)v;                  // v >= 0 so trunc == floor
        li = li < 0 ? 0 : (li > RESO - 2 ? RESO - 2 : li);
        l[i] = li;
        wb[i] = v - (float)li;
    }

    const int dz = 1;
    const int dy = RESO;
    const int dx = RESO * RESO;
    const int base = (l[0] * RESO + l[1]) * RESO + l[2];

    int lk[8];
    lk[0] = links[base];
    lk[1] = links[base + dz];
    lk[2] = links[base + dy];
    lk[3] = links[base + dy + dz];
    lk[4] = links[base + dx];
    lk[5] = links[base + dx + dz];
    lk[6] = links[base + dx + dy];
    lk[7] = links[base + dx + dy + dz];

    float4 cv[8];
#pragma unroll
    for (int k = 0; k < 8; ++k) {
        if (lk[k] >= 0) {
            cv[k] = *reinterpret_cast<const float4*>(
                data + (size_t)lk[k] * DATA_DIM + (size_t)c * 4);
        } else {
            cv[k] = f4_zero();
        }
    }

    const float waz = 1.0f - wb[2], wbz = wb[2];
    const float way = 1.0f - wb[1], wby = wb[1];
    const float wax = 1.0f - wb[0], wbx = wb[0];

    float4 c00 = f4_lerp(cv[0], cv[1], waz, wbz);
    float4 c01 = f4_lerp(cv[2], cv[3], waz, wbz);
    float4 c10 = f4_lerp(cv[4], cv[5], waz, wbz);
    float4 c11 = f4_lerp(cv[6], cv[7], waz, wbz);

    float4 c0 = f4_lerp(c00, c01, way, wby);
    float4 c1 = f4_lerp(c10, c11, way, wby);

    float4 s = f4_lerp(c0, c1, wax, wbx);

    // out index = p*28 + c*4 == tid*4 -> fully contiguous float4 stream
    *reinterpret_cast<float4*>(out + (size_t)tid * 4) = s;
}

extern "C" void kernel_launch(void* const* d_in, const int* in_sizes, int n_in,
                              void* d_out, int out_size, void* d_ws, size_t ws_size,
                              hipStream_t stream)
{
    const float* points  = (const float*)d_in[0];
    const float* data    = (const float*)d_in[1];
    const int*   links   = (const int*)d_in[2];
    const float* offset  = (const float*)d_in[3];
    const float* scaling = (const float*)d_in[4];
    float*       out     = (float*)d_out;

    const int n_pts = in_sizes[0] / 3;
    const int total = n_pts * CHUNKS;
    const int block = 256;
    const int grid  = (total + block - 1) / block;

    sparsegrid_sample_kernel<<<grid, block, 0, stream>>>(
        points, data, links, offset, scaling, out, n_pts);
}